// Round 1
// baseline (2405.472 us; speedup 1.0000x reference)
//
#include <hip/hip_runtime.h>
#include <hip/hip_fp16.h>
#include <cstdint>
#include <cstddef>

#define BB  256
#define TT  2048
#define KIN 182
#define HH  64
#define G3  192   // 3*H

// ---- workspace layout ----
#define WIHT_BYTES ((size_t)KIN * G3 * 4)          // 139776 (multiple of 256)
#define IG_OFF     WIHT_BYTES
#define IG_BYTES   ((size_t)BB * TT * G3 * 2)      // 201,326,592 (fp16)
#define WS_NEEDED  (IG_OFF + IG_BYTES)

// Transpose W_ih (192x182 row-major) -> WihT (182x192) so GEMM weight reads coalesce.
__global__ __launch_bounds__(256) void prep_wihT(const float* __restrict__ wih,
                                                 float* __restrict__ wihT) {
    int idx = blockIdx.x * 256 + threadIdx.x;
    if (idx < G3 * KIN) {
        int j = idx / KIN, k = idx - j * KIN;
        wihT[k * G3 + j] = wih[idx];
    }
}

// IG = x @ W_ih^T + bias, stored fp16. One block = 32 rows (timesteps) x all 192 cols.
// Thread j owns column j; x tile staged transposed in LDS (pad 36 for alignment+banks).
__global__ __launch_bounds__(192) void ig_gemm(const float* __restrict__ x,
                                               const float* __restrict__ wihT,
                                               const float* __restrict__ bias,
                                               __half* __restrict__ ig) {
    __shared__ float xs[KIN * 36];
    const int j = threadIdx.x;
    const size_t r0 = (size_t)blockIdx.x * 32;

    for (int idx = j; idx < 32 * KIN; idx += 192) {
        int t = idx / KIN, k = idx - t * KIN;
        xs[k * 36 + t] = x[r0 * KIN + idx];      // global read is fully coalesced
    }
    __syncthreads();

    float acc[32];
#pragma unroll
    for (int t = 0; t < 32; ++t) acc[t] = 0.f;

#pragma unroll 2
    for (int k = 0; k < KIN; ++k) {
        float w = wihT[k * G3 + j];              // coalesced, L2-resident
        const float4* xv = (const float4*)(&xs[k * 36]);
#pragma unroll
        for (int t4 = 0; t4 < 8; ++t4) {
            float4 v = xv[t4];                   // broadcast LDS b128 reads
            acc[4 * t4 + 0] += w * v.x;
            acc[4 * t4 + 1] += w * v.y;
            acc[4 * t4 + 2] += w * v.z;
            acc[4 * t4 + 3] += w * v.w;
        }
    }
    float bj = bias[j];
#pragma unroll
    for (int t = 0; t < 32; ++t)
        ig[(r0 + t) * G3 + j] = __float2half(acc[t] + bj);
}

// Sequential GRU scan. One block per batch, 192 threads: thread j owns W_hh row j
// (64 fp32 in registers). Per step: dot vs h (LDS broadcast), gate exchange via LDS,
// exactly 2 barriers. IG prefetched 4 steps ahead in registers.
__global__ __launch_bounds__(192) void gru_scan(const float* __restrict__ whh,
                                                const float* __restrict__ bias_n,
                                                const __half* __restrict__ ig,
                                                const float* __restrict__ wout,
                                                const float* __restrict__ outb,
                                                float* __restrict__ out) {
    const int j = threadIdx.x;
    const int i = j & 63;
    const int b = blockIdx.x;

    __shared__ float hbuf[HH];
    __shared__ float Abuf[G3];   // r,z rows: ig+hg ; n rows: hg+bias_n
    __shared__ float Bbuf[HH];   // ig_n

    float w[HH];
#pragma unroll
    for (int k = 0; k < HH; k += 4) {
        float4 v = *(const float4*)(whh + j * HH + k);
        w[k] = v.x; w[k + 1] = v.y; w[k + 2] = v.z; w[k + 3] = v.w;
    }
    const float bn = bias_n[i];
    if (j < HH) hbuf[j] = 0.f;
    __syncthreads();

    const __half* cur = ig + (size_t)b * TT * G3 + j;

    auto step = [&](float pv) {
        // hg_j = W_hh[j,:] . h   (4 independent FMA chains for ILP)
        float s0 = 0.f, s1 = 0.f, s2 = 0.f, s3 = 0.f;
        const float4* h4 = (const float4*)hbuf;
#pragma unroll
        for (int k = 0; k < 16; ++k) {
            float4 hv = h4[k];                   // broadcast LDS reads
            s0 += w[4 * k + 0] * hv.x;
            s1 += w[4 * k + 1] * hv.y;
            s2 += w[4 * k + 2] * hv.z;
            s3 += w[4 * k + 3] * hv.w;
        }
        float hg = (s0 + s1) + (s2 + s3);
        float hi = hbuf[i];                      // old h, read before any write
        Abuf[j] = (j < 128) ? (pv + hg) : (hg + bn);
        if (j >= 128) Bbuf[i] = pv;              // ig_n (bias already folded in)
        __syncthreads();                         // barrier 1: gates visible
        if (j < HH) {
            float ar = Abuf[j], az = Abuf[HH + j], an = Abuf[128 + j], bv = Bbuf[j];
            float r = 1.f / (1.f + __expf(-ar));
            float z = 1.f / (1.f + __expf(-az));
            float e = __expf(2.f * (bv + r * an));   // tanh(x)=1-2/(e^{2x}+1)
            float nn = 1.f - 2.f / (e + 1.f);
            hbuf[j] = nn + z * (hi - nn);        // safe: all hbuf reads were pre-barrier1
        }
        __syncthreads();                         // barrier 2: new h + free A/B bufs
    };

    float p0 = __half2float(cur[0]);
    float p1 = __half2float(cur[G3]);
    float p2 = __half2float(cur[2 * G3]);
    float p3 = __half2float(cur[3 * G3]);
    for (int t = 0; t < TT; t += 4) {
        const __half* nxt = cur + 4 * G3;
        float q0, q1, q2, q3;
        if (t + 4 < TT) {                        // rolling prefetch, ~1600 cyc lead
            q0 = __half2float(nxt[0]);
            q1 = __half2float(nxt[G3]);
            q2 = __half2float(nxt[2 * G3]);
            q3 = __half2float(nxt[3 * G3]);
        } else { q0 = q1 = q2 = q3 = 0.f; }
        step(p0); step(p1); step(p2); step(p3);
        p0 = q0; p1 = q1; p2 = q2; p3 = q3;
        cur = nxt;
    }

    // readout: sigmoid(h @ w_out^T + out_bias), 2 outputs per batch
    if (j < 2) {
        float s = 0.f;
#pragma unroll
        for (int k = 0; k < HH; ++k) s += wout[j * HH + k] * hbuf[k];
        float yv = s + outb[j];
        out[b * 2 + j] = 1.f / (1.f + __expf(-yv));
    }
}

extern "C" void kernel_launch(void* const* d_in, const int* in_sizes, int n_in,
                              void* d_out, int out_size, void* d_ws, size_t ws_size,
                              hipStream_t stream) {
    const float* x     = (const float*)d_in[0];
    const float* wih   = (const float*)d_in[1];
    const float* whh   = (const float*)d_in[2];
    const float* bias  = (const float*)d_in[3];
    const float* biasn = (const float*)d_in[4];
    const float* wout  = (const float*)d_in[5];
    const float* outb  = (const float*)d_in[6];
    float* out = (float*)d_out;

    if (ws_size < WS_NEEDED) {
        // Distinguishable failure: NaN sentinel => ws_size shortfall, not a logic bug.
        hipMemsetAsync(d_out, 0xFF, (size_t)out_size * sizeof(float), stream);
        return;
    }
    float*  wihT  = (float*)d_ws;
    __half* igbuf = (__half*)((char*)d_ws + IG_OFF);

    prep_wihT<<<(G3 * KIN + 255) / 256, 256, 0, stream>>>(wih, wihT);
    ig_gemm<<<(BB * TT) / 32, 192, 0, stream>>>(x, wihT, bias, igbuf);
    gru_scan<<<BB, 192, 0, stream>>>(whh, biasn, igbuf, wout, outb, out);
}

// Round 2
// 1875.116 us; speedup vs baseline: 1.2828x; 1.2828x over previous
//
#include <hip/hip_runtime.h>
#include <hip/hip_fp16.h>
#include <cstdint>
#include <cstddef>

#define BB  256
#define TT  2048
#define KIN 182
#define HH  64
#define G3  192   // 3*H

#define IG_BYTES ((size_t)BB * TT * G3 * 2)   // fp16 IG buffer
#define WS_NEEDED IG_BYTES

typedef _Float16 half8 __attribute__((ext_vector_type(8)));
typedef float    f32x4 __attribute__((ext_vector_type(4)));
typedef float    v2f   __attribute__((ext_vector_type(2)));

#define TILES_PER_BLOCK 16
#define GEMM_BLOCKS (BB * TT / 16 / TILES_PER_BLOCK)   // 2048

// ---------------------------------------------------------------------------
// IG = fp16( x @ W_ih^T + bias ), via mfma_f32_16x16x32_f16.
// Block = 256 thr (4 waves). Wave w owns gate-cols n in [48w, 48w+48):
// B-frags (W_ih^T) persistent in registers (18 frags = 72 VGPRs).
// A (x rows) staged fp32->fp16 in LDS, stride 200 halves (2-way banks = free).
// ---------------------------------------------------------------------------
__global__ __launch_bounds__(256, 3) void ig_gemm(const float* __restrict__ x,
                                                  const float* __restrict__ wih,
                                                  const float* __restrict__ bias,
                                                  __half* __restrict__ ig) {
    __shared__ _Float16 As[16][200];
    const int tid  = threadIdx.x;
    const int lane = tid & 63;
    const int w    = tid >> 6;
    const int col  = lane & 15;   // m for A-frag / n for B,D-frag
    const int kq   = lane >> 4;   // 0..3

    // zero the K-pad columns [182,200) once; staging never touches them
    for (int idx = tid; idx < 16 * 18; idx += 256) {
        int m = idx / 18, k = 182 + (idx - (idx / 18) * 18);
        As[m][k] = (_Float16)0.f;
    }

    // persistent B fragments: B[k][n] = wih[n][k], zero-padded k in [182,192)
    half8 bf[3][6];
    float bv[3];
#pragma unroll
    for (int nt = 0; nt < 3; ++nt) {
        int n = 48 * w + 16 * nt + col;
        bv[nt] = bias[n];
#pragma unroll
        for (int kf = 0; kf < 6; ++kf) {
            int k0 = kf * 32 + kq * 8;
            half8 f;
#pragma unroll
            for (int j = 0; j < 8; ++j) {
                int k = k0 + j;
                f[j] = (_Float16)((k < KIN) ? wih[n * KIN + k] : 0.f);
            }
            bf[nt][kf] = f;
        }
    }

    for (int it = 0; it < TILES_PER_BLOCK; ++it) {
        const size_t r0 = ((size_t)blockIdx.x * TILES_PER_BLOCK + it) * 16;
        __syncthreads();                       // As free (prev iter fully read)
        for (int idx = tid; idx < 16 * KIN; idx += 256) {
            int m = idx / KIN, k = idx - m * KIN;
            As[m][k] = (_Float16)x[r0 * KIN + idx];   // coalesced b32 reads
        }
        __syncthreads();

        half8 af[6];
#pragma unroll
        for (int kf = 0; kf < 6; ++kf)
            af[kf] = *(const half8*)&As[col][kq * 8 + kf * 32];

#pragma unroll
        for (int nt = 0; nt < 3; ++nt) {
            f32x4 c = {0.f, 0.f, 0.f, 0.f};
#pragma unroll
            for (int kf = 0; kf < 6; ++kf)
                c = __builtin_amdgcn_mfma_f32_16x16x32_f16(af[kf], bf[nt][kf], c, 0, 0, 0);
            int n    = 48 * w + 16 * nt + col;
            int row0 = kq * 4;
#pragma unroll
            for (int r = 0; r < 4; ++r)
                ig[(r0 + row0 + r) * G3 + n] = __float2half(c[r] + bv[nt]);
        }
    }
}

// ---------------------------------------------------------------------------
// GRU scan: ONE WAVE per batch, wave-synchronous (no s_barrier at all).
// Lane i owns h_i and all 3 gate rows i: W_hh rows in 192 VGPRs (v2f),
// h broadcast through 256 B of LDS (16 b128 broadcast reads/step).
// ---------------------------------------------------------------------------
__global__ __launch_bounds__(64, 1) void gru_scan(const float* __restrict__ whh,
                                                  const float* __restrict__ bias_n,
                                                  const __half* __restrict__ ig,
                                                  const float* __restrict__ wout,
                                                  const float* __restrict__ outb,
                                                  float* __restrict__ out) {
    const int i = threadIdx.x;   // 0..63, lane == thread
    const int b = blockIdx.x;
    __shared__ float hs[HH];

    v2f wr[32], wz[32], wn[32];
    {
        const v2f* pr = (const v2f*)(whh + (size_t)(0 * HH + i) * HH);
        const v2f* pz = (const v2f*)(whh + (size_t)(1 * HH + i) * HH);
        const v2f* pn = (const v2f*)(whh + (size_t)(2 * HH + i) * HH);
#pragma unroll
        for (int k = 0; k < 32; ++k) { wr[k] = pr[k]; wz[k] = pz[k]; wn[k] = pn[k]; }
    }
    const float bn = bias_n[i];
    float h = 0.f;
    hs[i] = 0.f;
    __builtin_amdgcn_wave_barrier();

    const __half* base = ig + (size_t)b * TT * G3 + i;

    auto step = [&](float pr_, float pz_, float pn_) {
        v2f a0{0.f,0.f}, a1{0.f,0.f}, z0{0.f,0.f}, z1{0.f,0.f}, n0{0.f,0.f}, n1{0.f,0.f};
        const v2f* h2 = (const v2f*)hs;
#pragma unroll
        for (int k = 0; k < 16; ++k) {         // 96 packed fmas, 6 ILP chains
            v2f hA = h2[2 * k], hB = h2[2 * k + 1];
            a0 = wr[2 * k] * hA + a0;  a1 = wr[2 * k + 1] * hB + a1;
            z0 = wz[2 * k] * hA + z0;  z1 = wz[2 * k + 1] * hB + z1;
            n0 = wn[2 * k] * hA + n0;  n1 = wn[2 * k + 1] * hB + n1;
        }
        float sr = (a0.x + a0.y) + (a1.x + a1.y);
        float sz = (z0.x + z0.y) + (z1.x + z1.y);
        float sn = (n0.x + n0.y) + (n1.x + n1.y);
        float r  = 1.f / (1.f + __expf(-(pr_ + sr)));
        float z  = 1.f / (1.f + __expf(-(pz_ + sz)));
        float e  = __expf(2.f * (pn_ + r * (sn + bn)));   // tanh via exp
        float nn = 1.f - 2.f / (e + 1.f);
        h = nn + z * (h - nn);
        __builtin_amdgcn_wave_barrier();       // all h reads issued before write
        hs[i] = h;
        __builtin_amdgcn_wave_barrier();       // write ordered before next reads
    };

    // rolling 4-step prefetch of IG (raw halves; convert at use)
    __half p0r, p0z, p0n, p1r, p1z, p1n, p2r, p2z, p2n, p3r, p3z, p3n;
    auto ld = [&](int t, __half& r_, __half& z_, __half& n_) {
        const __half* p = base + (size_t)t * G3;
        r_ = p[0]; z_ = p[64]; n_ = p[128];
    };
    ld(0, p0r, p0z, p0n); ld(1, p1r, p1z, p1n);
    ld(2, p2r, p2z, p2n); ld(3, p3r, p3z, p3n);

    for (int t = 0; t < TT; t += 4) {
        __half q0r{}, q0z{}, q0n{}, q1r{}, q1z{}, q1n{};
        __half q2r{}, q2z{}, q2n{}, q3r{}, q3z{}, q3n{};
        if (t + 4 < TT) {
            ld(t + 4, q0r, q0z, q0n); ld(t + 5, q1r, q1z, q1n);
            ld(t + 6, q2r, q2z, q2n); ld(t + 7, q3r, q3z, q3n);
        }
        step(__half2float(p0r), __half2float(p0z), __half2float(p0n));
        step(__half2float(p1r), __half2float(p1z), __half2float(p1n));
        step(__half2float(p2r), __half2float(p2z), __half2float(p2n));
        step(__half2float(p3r), __half2float(p3z), __half2float(p3n));
        p0r = q0r; p0z = q0z; p0n = q0n;  p1r = q1r; p1z = q1z; p1n = q1n;
        p2r = q2r; p2z = q2z; p2n = q2n;  p3r = q3r; p3z = q3z; p3n = q3n;
    }

    // readout: sigmoid(h . w_out^T + out_bias), butterfly reduce over the wave
    float s0 = wout[i] * h, s1 = wout[HH + i] * h;
#pragma unroll
    for (int off = 32; off > 0; off >>= 1) {
        s0 += __shfl_down(s0, off);
        s1 += __shfl_down(s1, off);
    }
    if (i == 0) {
        out[2 * b]     = 1.f / (1.f + __expf(-(s0 + outb[0])));
        out[2 * b + 1] = 1.f / (1.f + __expf(-(s1 + outb[1])));
    }
}

extern "C" void kernel_launch(void* const* d_in, const int* in_sizes, int n_in,
                              void* d_out, int out_size, void* d_ws, size_t ws_size,
                              hipStream_t stream) {
    const float* x     = (const float*)d_in[0];
    const float* wih   = (const float*)d_in[1];
    const float* whh   = (const float*)d_in[2];
    const float* bias  = (const float*)d_in[3];
    const float* biasn = (const float*)d_in[4];
    const float* wout  = (const float*)d_in[5];
    const float* outb  = (const float*)d_in[6];
    float* out = (float*)d_out;

    if (ws_size < WS_NEEDED) {
        hipMemsetAsync(d_out, 0xFF, (size_t)out_size * sizeof(float), stream);
        return;
    }
    __half* igbuf = (__half*)d_ws;

    ig_gemm<<<GEMM_BLOCKS, 256, 0, stream>>>(x, wih, bias, igbuf);
    gru_scan<<<BB, 64, 0, stream>>>(whh, biasn, igbuf, wout, outb, out);
}